// Round 10
// baseline (179.309 us; speedup 1.0000x reference)
//
#include <hip/hip_runtime.h>

// MHA forward, round 10: LDS-free attention (global->register fragments,
// zero barriers, 32 q/wave) + A-operand-in-registers GEMMs (LDS stages B only).
// B=2, S=2048, D=1024, H=16, DH=64, scale=1/32 folded into exp2 constant.
//
// Pipeline (4 kernels):
//   0) prep:       cast x->bf16 + transpose W->Wt
//   1) gemm2ph<0>: fused QKV, grid 768, B-only dbuf LDS, A via registers.
//   2) attn_nolds: causal flash attn, wave-independent, grid 512.
//   3) gemm2ph<1>: Ab @ Wto^T -> d_out fp32, grid 256.
//
// ws: xb 8@0 | Wt 8@8 | Qb 8@16 | Kb 8@24 | Vp 8@32 | Ab 8@40  (48MB)

#define AS1 __attribute__((address_space(1)))
#define AS3 __attribute__((address_space(3)))
#define EXPC2 0.04508422f  // (1/32) * log2(e)

typedef __attribute__((ext_vector_type(4))) float f32x4;
typedef __attribute__((ext_vector_type(8))) short bf16x8;

__device__ __forceinline__ void gload16(const void* g, void* l) {
  __builtin_amdgcn_global_load_lds((const AS1 unsigned int*)g,
                                   (AS3 unsigned int*)l, 16, 0, 0);
}
__device__ __forceinline__ unsigned short f2b(float f) {  // RNE fp32->bf16
  unsigned u = __float_as_uint(f);
  return (unsigned short)((u + 0x7FFFu + ((u >> 16) & 1u)) >> 16);
}
__device__ __forceinline__ float fexp2(float x) {
  float r;
  asm("v_exp_f32 %0, %1" : "=v"(r) : "v"(x));
  return r;
}
__device__ __forceinline__ unsigned cvtpk(float a, float b) {  // [a|b] bf16x2
  unsigned r;
  asm("v_cvt_pk_bf16_f32 %0, %1, %2" : "=v"(r) : "v"(a), "v"(b));
  return r;
}

// ---------------------------------------------------------------- prep ----
__global__ __launch_bounds__(256) void prep(
    const float* __restrict__ x, const float* __restrict__ W0,
    const float* __restrict__ W1, const float* __restrict__ W2,
    const float* __restrict__ W3, unsigned short* __restrict__ xb,
    unsigned short* __restrict__ Wt) {
  __shared__ float T[64][65];
  const int tid = threadIdx.x;
  const int bid = blockIdx.x;
  if (bid < 4096) {
    const size_t i = (size_t)(bid * 256 + tid) * 4;
    float4 v = *(const float4*)&x[i];
    uint2 o;
    o.x = f2b(v.x) | ((unsigned)f2b(v.y) << 16);
    o.y = f2b(v.z) | ((unsigned)f2b(v.w) << 16);
    *(uint2*)&xb[i] = o;
    return;
  }
  const int idx = bid - 4096;
  const int kb = (idx & 15) * 64, nb = ((idx >> 4) & 15) * 64, z = idx >> 8;
  const float* W = (z == 0) ? W0 : (z == 1) ? W1 : (z == 2) ? W2 : W3;
  unsigned short* D = Wt + (size_t)z * 1024 * 1024;
#pragma unroll
  for (int p = 0; p < 4; ++p) {
    const int s = p * 256 + tid;
    const int r = s >> 4, c4 = s & 15;
    float4 v = *(const float4*)&W[(size_t)(kb + r) * 1024 + nb + c4 * 4];
    T[r][c4 * 4 + 0] = v.x;
    T[r][c4 * 4 + 1] = v.y;
    T[r][c4 * 4 + 2] = v.z;
    T[r][c4 * 4 + 3] = v.w;
  }
  __syncthreads();
#pragma unroll
  for (int p = 0; p < 4; ++p) {
    const int s = p * 256 + tid;
    const int n = s >> 4, k4 = s & 15;
    uint2 o;
    o.x = f2b(T[k4 * 4 + 0][n]) | ((unsigned)f2b(T[k4 * 4 + 1][n]) << 16);
    o.y = f2b(T[k4 * 4 + 2][n]) | ((unsigned)f2b(T[k4 * 4 + 3][n]) << 16);
    *(uint2*)&D[(size_t)(nb + n) * 1024 + kb + k4 * 4] = o;
  }
}

// ----------------------------------------------------- 2-phase bf16 GEMM ----
// 128x128 tile, BK=32, 4 waves. B staged in dbuf LDS (round-9 swizzle);
// A fragments loaded global->register, double-buffered one K-step ahead.
// KIND 0: fused QKV. grid 768 linear, bn = id%24, bm = id/24.
// KIND 1: out GEMM. grid 256 linear.
template <int KIND>
__global__ __launch_bounds__(256) void gemm2ph(
    const unsigned short* __restrict__ A, const unsigned short* __restrict__ B,
    unsigned short* __restrict__ Qb, unsigned short* __restrict__ Kb,
    unsigned short* __restrict__ Vp, float* __restrict__ Of) {
  // B dbuf: buf0 @0, buf1 @4096 (ushort idx). V slab [128][132] = 16896 aliases.
  __shared__ unsigned short smem[16896];

  const int tid = threadIdx.x, lane = tid & 63, w = tid >> 6;
  int bm, bn;
  if constexpr (KIND == 0) {
    bm = blockIdx.x / 24;
    bn = blockIdx.x % 24;
  } else {
    bm = blockIdx.x >> 3;
    bn = blockIdx.x & 7;
  }
  const int wr = w >> 1, wc = w & 1;

  f32x4 acc[4][4];
#pragma unroll
  for (int m = 0; m < 4; ++m)
#pragma unroll
    for (int n = 0; n < 4; ++n) acc[m][n] = (f32x4)0.0f;

  // B staging source swizzle (write side; round-9 verified involution)
  const int lu = (lane & 7) ^ (lane >> 3);
  const int srow2 = 2 * (lane >> 3) + (lu >> 2);
  const int scol2 = (lu & 3) * 8;
  const size_t brow = (size_t)(bn * 128 + srow2) * 1024 + scol2;

  // B fragment read swizzle (read side)
  const int fr = lane & 15, g = lane >> 4;
  const int fh = fr >> 1;
  const int pcx = ((((fr & 1) << 2) | g) ^ fh) * 8;

  // A fragments direct from global: row bm*128 + wr*64 + m*16 + fr, k g*8..
  const size_t aFragBase = (size_t)(bm * 128 + wr * 64 + fr) * 1024 + g * 8;
  bf16x8 afA[4], afB[4];
#pragma unroll
  for (int m = 0; m < 4; ++m)
    afA[m] = *(const bf16x8*)&A[aFragBase + (size_t)m * 16384];

#define GSTAGE(BUF, KC)                                                      \
  {                                                                          \
    _Pragma("unroll") for (int q = 0; q < 2; ++q) {                          \
      const int r = w * 32 + q * 16;                                         \
      gload16(&B[brow + (size_t)r * 1024 + (KC)],                            \
              &smem[(BUF) * 4096 + r * 32]);                                 \
    }                                                                        \
  }

#define GSTEP(T, AC, AN)                                                     \
  {                                                                          \
    __syncthreads(); /* B buf[(T)&1] resident; prev A-regs landed */         \
    if ((T) + 1 < 32) {                                                      \
      GSTAGE(((T) + 1) & 1, ((T) + 1) * 32)                                  \
      _Pragma("unroll") for (int m = 0; m < 4; ++m) AN[m] =                  \
          *(const bf16x8*)&A[aFragBase + (size_t)m * 16384 + ((T) + 1) * 32];\
    }                                                                        \
    bf16x8 bf[4];                                                            \
    _Pragma("unroll") for (int n = 0; n < 4; ++n) bf[n] =                    \
        *(const bf16x8*)&smem[((T)&1) * 4096 + (wc * 32 + n * 8 + fh) * 64 + \
                              pcx];                                          \
    _Pragma("unroll") for (int m = 0; m < 4; ++m)                            \
        _Pragma("unroll") for (int n = 0; n < 4; ++n) acc[m][n] =            \
            __builtin_amdgcn_mfma_f32_16x16x32_bf16(AC[m], bf[n], acc[m][n], \
                                                    0, 0, 0);                \
  }

  GSTAGE(0, 0)
  for (int t = 0; t < 32; t += 2) {
    GSTEP(t, afA, afB)
    GSTEP(t + 1, afB, afA)
  }

  const int fq = lane >> 4;
  if constexpr (KIND == 1) {
#pragma unroll
    for (int mf = 0; mf < 4; ++mf)
#pragma unroll
      for (int nf = 0; nf < 4; ++nf) {
        const int col = bn * 128 + wc * 64 + nf * 16 + fr;
#pragma unroll
        for (int rr = 0; rr < 4; ++rr) {
          const int m = bm * 128 + wr * 64 + mf * 16 + fq * 4 + rr;
          Of[(size_t)m * 1024 + col] = acc[mf][nf][rr];
        }
      }
    return;
  } else if (bn < 16) {
    // ---- Q / K scatter epilogue ----
    unsigned short* Ob = (bn < 8) ? Qb : Kb;
    const int cbase = (bn & 7) * 128;
#pragma unroll
    for (int mf = 0; mf < 4; ++mf)
#pragma unroll
      for (int nf = 0; nf < 4; ++nf) {
        const int col = cbase + wc * 64 + nf * 16 + fr;
        const int h = col >> 6, d = col & 63;
#pragma unroll
        for (int rr = 0; rr < 4; ++rr) {
          const int m = bm * 128 + wr * 64 + mf * 16 + fq * 4 + rr;
          const int b = m >> 11, s = m & 2047;
          Ob[((size_t)(b * 16 + h) * 2048 + s) * 64 + d] = f2b(acc[mf][nf][rr]);
        }
      }
    return;
  }

  // ---- V epilogue: LDS-transpose slab [cl 128][sperm 132] ----
  __syncthreads();  // all ds_reads done -> safe to alias slab
#pragma unroll
  for (int mf = 0; mf < 4; ++mf)
#pragma unroll
    for (int nf = 0; nf < 4; ++nf) {
      const int cl = wc * 64 + nf * 16 + fr;  // local (h,d) col 0..127
#pragma unroll
      for (int rr = 0; rr < 4; ++rr) {
        const int ml = wr * 64 + mf * 16 + fq * 4 + rr;  // local s 0..127
        const int u = ml & 63, a = u >> 4;
        const int sperm = (ml & 64) | ((a >> 1) * 32 + ((u >> 2) & 3) * 8 +
                                       (a & 1) * 4 + (u & 3));
        smem[cl * 132 + sperm] = f2b(acc[mf][nf][rr]);
      }
    }
  __syncthreads();
  const int l5 = lane & 31;
  const size_t sbase = (size_t)((bm * 128) & 2047);
  const int bV = bm >> 4;
#pragma unroll
  for (int it = 0; it < 16; ++it) {
    const int rl = w * 32 + it * 2 + (lane >> 5);
    const int rowg = (bn - 16) * 128 + rl;
    const int h = rowg >> 6, d = rowg & 63;
    uint2 v = *(const uint2*)&smem[rl * 132 + l5 * 4];
    *(uint2*)&Vp[((size_t)(bV * 16 + h) * 64 + d) * 2048 + sbase + l5 * 4] = v;
  }
#undef GSTEP
#undef GSTAGE
}

// ----------------------------------------------------------- attention ----
// Wave-independent, zero LDS/barriers. Each wave owns 32 q-rows (t32 q-tile),
// kv-tile 64. K fragments prefetched into ping-pong registers; V issued early.
// Dispatch: id&7 = XCD -> bh group of 4 (K/V 2MB L2-resident per XCD);
// (h8, 23-h8) folding pairs block lengths (p, 15-p) on each CU.
// Swapped MFMA: S^T = K.Q^T, P in-register (sigma-matched Vp), O^T accum.
__global__ __launch_bounds__(256) void attn_nolds(
    const unsigned short* __restrict__ Qb, const unsigned short* __restrict__ Kb,
    const unsigned short* __restrict__ Vp, unsigned short* __restrict__ Ab) {
  const int tid = threadIdx.x, lane = tid & 63, w = tid >> 6;
  const int lo = lane & 15, hi = lane >> 4;

  const int id = blockIdx.x;
  const int xcd = id & 7, mm = id >> 3;
  const int bh = xcd * 4 + (mm & 3);
  const int h8 = mm >> 2;                       // 0..15
  const int bq4 = (h8 < 8) ? h8 : 23 - h8;      // pairs (p, 15-p) per CU
  const int t32 = bq4 * 4 + w;                  // q-tile-32 index 0..63
  const int qw = t32 * 32;
  const int ntile = (t32 >> 1) + 1;
  const size_t base = (size_t)bh * (2048 * 64);
  const unsigned short* kg = Kb + base;
  const unsigned short* vg = Vp + base;

  // Q as B-operand: col q = lo (per qn frag), rows d = ks*32 + hi*8 + j
  bf16x8 qf[2][2];
#pragma unroll
  for (int qn = 0; qn < 2; ++qn)
#pragma unroll
    for (int ks = 0; ks < 2; ++ks)
      qf[qn][ks] = *(const bf16x8*)&Qb[base +
                                       (size_t)(qw + qn * 16 + lo) * 64 +
                                       ks * 32 + hi * 8];

  f32x4 accO[4][2];  // O^T: row d = mf*16+hi*4+rr, col q = lo (per qn)
#pragma unroll
  for (int mf = 0; mf < 4; ++mf)
#pragma unroll
    for (int qn = 0; qn < 2; ++qn) accO[mf][qn] = (f32x4)0.0f;
  float mrow[2] = {-1e30f, -1e30f}, lpart[2] = {0.0f, 0.0f};

  bf16x8 kaA[2][4], kaB[2][4];
#define LOADK(DST, KB_)                                                      \
  _Pragma("unroll") for (int ks = 0; ks < 2; ++ks)                           \
      _Pragma("unroll") for (int kf = 0; kf < 4; ++kf) DST[ks][kf] =         \
          *(const bf16x8*)&kg[(size_t)((KB_) + kf * 16 + lo) * 64 +          \
                              ks * 32 + hi * 8];

#define ATILE(T, KA, KN)                                                     \
  {                                                                          \
    const int kb = (T) * 64;                                                 \
    f32x4 st[4][2];                                                          \
    _Pragma("unroll") for (int kf = 0; kf < 4; ++kf)                         \
        _Pragma("unroll") for (int qn = 0; qn < 2; ++qn) st[kf][qn] =        \
            (f32x4)0.0f;                                                     \
    __builtin_amdgcn_s_setprio(1);                                           \
    _Pragma("unroll") for (int ks = 0; ks < 2; ++ks)                         \
        _Pragma("unroll") for (int kf = 0; kf < 4; ++kf)                     \
            _Pragma("unroll") for (int qn = 0; qn < 2; ++qn) st[kf][qn] =    \
                __builtin_amdgcn_mfma_f32_16x16x32_bf16(                     \
                    KA[ks][kf], qf[qn][ks], st[kf][qn], 0, 0, 0);            \
    __builtin_amdgcn_s_setprio(0);                                           \
    if ((T) + 1 < ntile) LOADK(KN, ((T) + 1) * 64)                           \
    bf16x8 va[2][4]; /* V^T rows d, sigma-permuted cols -> pb alignment */   \
    _Pragma("unroll") for (int ks = 0; ks < 2; ++ks)                         \
        _Pragma("unroll") for (int mf = 0; mf < 4; ++mf) va[ks][mf] =        \
            *(const bf16x8*)&vg[(size_t)(mf * 16 + lo) * 2048 + kb +         \
                                ks * 32 + hi * 8];                           \
    bf16x8 pb[2][2];                                                         \
    _Pragma("unroll") for (int qn = 0; qn < 2; ++qn) {                       \
      float v[16];                                                           \
      _Pragma("unroll") for (int kf = 0; kf < 4; ++kf)                       \
          _Pragma("unroll") for (int rr = 0; rr < 4; ++rr) v[kf * 4 + rr] =  \
              st[kf][qn][rr];                                                \
      if (kb + 63 > qw) {                                                    \
        const int qg = qw + qn * 16 + lo;                                    \
        _Pragma("unroll") for (int kf = 0; kf < 4; ++kf)                     \
            _Pragma("unroll") for (int rr = 0; rr < 4; ++rr) if (kb +        \
                kf * 16 + hi * 4 + rr > qg) v[kf * 4 + rr] = -1e30f;         \
      }                                                                      \
      float mx = fmaxf(fmaxf(fmaxf(v[0], v[1]), fmaxf(v[2], v[3])),          \
                       fmaxf(fmaxf(v[4], v[5]), fmaxf(v[6], v[7])));         \
      mx = fmaxf(mx, fmaxf(fmaxf(fmaxf(v[8], v[9]), fmaxf(v[10], v[11])),    \
                           fmaxf(fmaxf(v[12], v[13]), fmaxf(v[14], v[15]))));\
      mx = fmaxf(mx, __shfl_xor(mx, 16));                                    \
      mx = fmaxf(mx, __shfl_xor(mx, 32));                                    \
      if (!__all(mx - mrow[qn] <= 64.0f)) { /* T13 defer-rescale */          \
        const float mnew = fmaxf(mrow[qn], mx);                              \
        const float al = fexp2((mrow[qn] - mnew) * EXPC2);                   \
        mrow[qn] = mnew;                                                     \
        lpart[qn] *= al;                                                     \
        _Pragma("unroll") for (int mf = 0; mf < 4; ++mf)                     \
            _Pragma("unroll") for (int rr = 0; rr < 4; ++rr)                 \
                accO[mf][qn][rr] *= al;                                      \
      }                                                                      \
      float p[16], rs = 0.0f;                                                \
      _Pragma("unroll") for (int i = 0; i < 16; ++i) {                       \
        p[i] = fexp2((v[i] - mrow[qn]) * EXPC2);                             \
        rs += p[i];                                                          \
      }                                                                      \
      lpart[qn] += rs;                                                       \
      _Pragma("unroll") for (int ks = 0; ks < 2; ++ks) {                     \
        uint4 u;                                                             \
        u.x = cvtpk(p[ks * 8 + 0], p[ks * 8 + 1]);                           \
        u.y = cvtpk(p[ks * 8 + 2], p[ks * 8 + 3]);                           \
        u.z = cvtpk(p[ks * 8 + 4], p[ks * 8 + 5]);                           \
        u.w = cvtpk(p[ks * 8 + 6], p[ks * 8 + 7]);                           \
        pb[qn][ks] = *(bf16x8*)&u;                                           \
      }                                                                      \
    }                                                                        \
    __builtin_amdgcn_s_setprio(1);                                           \
    _Pragma("unroll") for (int ks = 0; ks < 2; ++ks)                         \
        _Pragma("unroll") for (int mf = 0; mf < 4; ++mf)                     \
            _Pragma("unroll") for (int qn = 0; qn < 2; ++qn) accO[mf][qn] =  \
                __builtin_amdgcn_mfma_f32_16x16x32_bf16(                     \
                    va[ks][mf], pb[qn][ks], accO[mf][qn], 0, 0, 0);          \
    __builtin_amdgcn_s_setprio(0);                                           \
  }

  LOADK(kaA, 0)
  int t = 0;
  while (true) {
    ATILE(t, kaA, kaB)
    if (++t >= ntile) break;
    ATILE(t, kaB, kaA)
    if (++t >= ntile) break;
  }

  // epilogue: denominator across hi-lanes, normalize, register-direct store
  const int b = bh >> 4, h = bh & 15;
#pragma unroll
  for (int qn = 0; qn < 2; ++qn) {
    float l = lpart[qn];
    l += __shfl_xor(l, 16);
    l += __shfl_xor(l, 32);
    const float linv = 1.0f / l;
#pragma unroll
    for (int mf = 0; mf < 4; ++mf) {
      uint2 u;
      u.x = cvtpk(accO[mf][qn][0] * linv, accO[mf][qn][1] * linv);
      u.y = cvtpk(accO[mf][qn][2] * linv, accO[mf][qn][3] * linv);
      *(uint2*)&Ab[(size_t)(b * 2048 + qw + qn * 16 + lo) * 1024 + h * 64 +
                   mf * 16 + hi * 4] = u;
    }
  }
#undef ATILE
#undef LOADK
}

// -------------------------------------------------------------- launch ----
extern "C" void kernel_launch(void* const* d_in, const int* in_sizes, int n_in,
                              void* d_out, int out_size, void* d_ws,
                              size_t ws_size, hipStream_t stream) {
  (void)in_sizes; (void)n_in; (void)out_size; (void)ws_size;
  const float* x = (const float*)d_in[0];
  const float* Wq = (const float*)d_in[1];
  const float* Wk = (const float*)d_in[2];
  const float* Wv = (const float*)d_in[3];
  const float* Wo = (const float*)d_in[4];
  float* out = (float*)d_out;

  char* ws = (char*)d_ws;
  unsigned short* xb = (unsigned short*)(ws);                // 8MB
  unsigned short* Wt = (unsigned short*)(ws + (8u << 20));   // 4x2MB (q,k,v,o)
  unsigned short* Qb = (unsigned short*)(ws + (16u << 20));  // 8MB
  unsigned short* Kb = (unsigned short*)(ws + (24u << 20));  // 8MB
  unsigned short* Vp = (unsigned short*)(ws + (32u << 20));  // 8MB
  unsigned short* Ab = (unsigned short*)(ws + (40u << 20));  // 8MB
  unsigned short* Wto = Wt + (size_t)3 * 1024 * 1024;        // ELEMENT offset

  prep<<<dim3(5120), 256, 0, stream>>>(x, Wq, Wk, Wv, Wo, xb, Wt);
  gemm2ph<0><<<dim3(768), 256, 0, stream>>>(xb, Wt, Qb, Kb, Vp, nullptr);
  attn_nolds<<<dim3(512), 256, 0, stream>>>(Qb, Kb, Vp, Ab);
  gemm2ph<1><<<dim3(256), 256, 0, stream>>>(Ab, Wto, nullptr, nullptr, nullptr,
                                            out);
}

// Round 11
// 146.946 us; speedup vs baseline: 1.2202x; 1.2202x over previous
//
#include <hip/hip_runtime.h>

// MHA forward, round 11: revert GEMMs to round-9 (known-good); attention A/B:
//   batch 0 (heads 0-15)  -> attn_q64  (round-9 LDS-staged, 4-wave blocks)
//   batch 1 (heads 16-31) -> attn_wave (1-wave 64-thread blocks, no LDS,
//                            reg-direct K/V, LPT order, XCD-local heads)
// B=2, S=2048, D=1024, H=16, DH=64, scale=1/32 folded into exp2 constant.
//
// ws: xb 8@0 | Wt 8@8 | Qb 8@16 | Kb 8@24 | Vp 8@32 | Ab 8@40  (48MB)

#define AS1 __attribute__((address_space(1)))
#define AS3 __attribute__((address_space(3)))
#define EXPC2 0.04508422f  // (1/32) * log2(e)

typedef __attribute__((ext_vector_type(4))) float f32x4;
typedef __attribute__((ext_vector_type(8))) short bf16x8;

__device__ __forceinline__ void gload16(const void* g, void* l) {
  __builtin_amdgcn_global_load_lds((const AS1 unsigned int*)g,
                                   (AS3 unsigned int*)l, 16, 0, 0);
}
__device__ __forceinline__ unsigned short f2b(float f) {  // RNE fp32->bf16
  unsigned u = __float_as_uint(f);
  return (unsigned short)((u + 0x7FFFu + ((u >> 16) & 1u)) >> 16);
}
__device__ __forceinline__ float fexp2(float x) {
  float r;
  asm("v_exp_f32 %0, %1" : "=v"(r) : "v"(x));
  return r;
}
__device__ __forceinline__ unsigned cvtpk(float a, float b) {  // [a|b] bf16x2
  unsigned r;
  asm("v_cvt_pk_bf16_f32 %0, %1, %2" : "=v"(r) : "v"(a), "v"(b));
  return r;
}

// ---------------------------------------------------------------- prep ----
__global__ __launch_bounds__(256) void prep(
    const float* __restrict__ x, const float* __restrict__ W0,
    const float* __restrict__ W1, const float* __restrict__ W2,
    const float* __restrict__ W3, unsigned short* __restrict__ xb,
    unsigned short* __restrict__ Wt) {
  __shared__ float T[64][65];
  const int tid = threadIdx.x;
  const int bid = blockIdx.x;
  if (bid < 4096) {
    const size_t i = (size_t)(bid * 256 + tid) * 4;
    float4 v = *(const float4*)&x[i];
    uint2 o;
    o.x = f2b(v.x) | ((unsigned)f2b(v.y) << 16);
    o.y = f2b(v.z) | ((unsigned)f2b(v.w) << 16);
    *(uint2*)&xb[i] = o;
    return;
  }
  const int idx = bid - 4096;
  const int kb = (idx & 15) * 64, nb = ((idx >> 4) & 15) * 64, z = idx >> 8;
  const float* W = (z == 0) ? W0 : (z == 1) ? W1 : (z == 2) ? W2 : W3;
  unsigned short* D = Wt + (size_t)z * 1024 * 1024;
#pragma unroll
  for (int p = 0; p < 4; ++p) {
    const int s = p * 256 + tid;
    const int r = s >> 4, c4 = s & 15;
    float4 v = *(const float4*)&W[(size_t)(kb + r) * 1024 + nb + c4 * 4];
    T[r][c4 * 4 + 0] = v.x;
    T[r][c4 * 4 + 1] = v.y;
    T[r][c4 * 4 + 2] = v.z;
    T[r][c4 * 4 + 3] = v.w;
  }
  __syncthreads();
#pragma unroll
  for (int p = 0; p < 4; ++p) {
    const int s = p * 256 + tid;
    const int n = s >> 4, k4 = s & 15;
    uint2 o;
    o.x = f2b(T[k4 * 4 + 0][n]) | ((unsigned)f2b(T[k4 * 4 + 1][n]) << 16);
    o.y = f2b(T[k4 * 4 + 2][n]) | ((unsigned)f2b(T[k4 * 4 + 3][n]) << 16);
    *(uint2*)&D[(size_t)(nb + n) * 1024 + kb + k4 * 4] = o;
  }
}

// ----------------------------------------------------- 2-phase bf16 GEMM ----
// Round-9 exact: 128x128 tile, BK=32, 4 waves, dbuf global_load_lds staging
// for A and B, row-pair-packed XOR-swizzled LDS layout.
template <int KIND>
__global__ __launch_bounds__(256) void gemm2ph(
    const unsigned short* __restrict__ A, const unsigned short* __restrict__ B,
    unsigned short* __restrict__ Qb, unsigned short* __restrict__ Kb,
    unsigned short* __restrict__ Vp, float* __restrict__ Of) {
  __shared__ unsigned short smem[16896];

  const int tid = threadIdx.x, lane = tid & 63, w = tid >> 6;
  int bm, bn;
  if constexpr (KIND == 0) {
    bm = blockIdx.x / 24;
    bn = blockIdx.x % 24;
  } else {
    bm = blockIdx.x >> 3;
    bn = blockIdx.x & 7;
  }
  const int wr = w >> 1, wc = w & 1;

  f32x4 acc[4][4];
#pragma unroll
  for (int m = 0; m < 4; ++m)
#pragma unroll
    for (int n = 0; n < 4; ++n) acc[m][n] = (f32x4)0.0f;

  // staging source swizzle (write side of the involution)
  const int lu = (lane & 7) ^ (lane >> 3);
  const int srow2 = 2 * (lane >> 3) + (lu >> 2);
  const int scol2 = (lu & 3) * 8;
  const size_t arow = (size_t)(bm * 128 + srow2) * 1024 + scol2;
  const size_t brow = (size_t)(bn * 128 + srow2) * 1024 + scol2;

  // fragment read swizzle (read side)
  const int fr = lane & 15, g = lane >> 4;
  const int fh = fr >> 1;
  const int pcx = ((((fr & 1) << 2) | g) ^ fh) * 8;

#define GSTAGE(BUF, KC)                                                      \
  {                                                                          \
    _Pragma("unroll") for (int q = 0; q < 2; ++q) {                          \
      const int r = w * 32 + q * 16;                                         \
      gload16(&A[arow + (size_t)r * 1024 + (KC)],                            \
              &smem[(BUF) * 8192 + r * 32]);                                 \
      gload16(&B[brow + (size_t)r * 1024 + (KC)],                            \
              &smem[(BUF) * 8192 + 4096 + r * 32]);                          \
    }                                                                        \
  }

  GSTAGE(0, 0)
  int cur = 0;

  for (int t = 0; t < 32; ++t) {
    __syncthreads();  // drains vmcnt -> buf[cur] resident
    if (t + 1 < 32) GSTAGE(cur ^ 1, (t + 1) * 32)

    bf16x8 af[4], bf[4];
#pragma unroll
    for (int m = 0; m < 4; ++m)
      af[m] = *(const bf16x8*)&smem[cur * 8192 + (wr * 32 + m * 8 + fh) * 64 +
                                    pcx];
#pragma unroll
    for (int n = 0; n < 4; ++n)
      bf[n] = *(const bf16x8*)&smem[cur * 8192 + 4096 +
                                    (wc * 32 + n * 8 + fh) * 64 + pcx];
#pragma unroll
    for (int m = 0; m < 4; ++m)
#pragma unroll
      for (int n = 0; n < 4; ++n)
        acc[m][n] = __builtin_amdgcn_mfma_f32_16x16x32_bf16(af[m], bf[n],
                                                            acc[m][n], 0, 0, 0);
    cur ^= 1;
  }

  const int fq = lane >> 4;
  if constexpr (KIND == 1) {
#pragma unroll
    for (int mf = 0; mf < 4; ++mf)
#pragma unroll
      for (int nf = 0; nf < 4; ++nf) {
        const int col = bn * 128 + wc * 64 + nf * 16 + fr;
#pragma unroll
        for (int rr = 0; rr < 4; ++rr) {
          const int m = bm * 128 + wr * 64 + mf * 16 + fq * 4 + rr;
          Of[(size_t)m * 1024 + col] = acc[mf][nf][rr];
        }
      }
    return;
  } else if (bn < 16) {
    unsigned short* Ob = (bn < 8) ? Qb : Kb;
    const int cbase = (bn & 7) * 128;
#pragma unroll
    for (int mf = 0; mf < 4; ++mf)
#pragma unroll
      for (int nf = 0; nf < 4; ++nf) {
        const int col = cbase + wc * 64 + nf * 16 + fr;
        const int h = col >> 6, d = col & 63;
#pragma unroll
        for (int rr = 0; rr < 4; ++rr) {
          const int m = bm * 128 + wr * 64 + mf * 16 + fq * 4 + rr;
          const int b = m >> 11, s = m & 2047;
          Ob[((size_t)(b * 16 + h) * 2048 + s) * 64 + d] = f2b(acc[mf][nf][rr]);
        }
      }
    return;
  }

  // V epilogue: LDS-transpose slab [cl 128][sperm 132]
  __syncthreads();
#pragma unroll
  for (int mf = 0; mf < 4; ++mf)
#pragma unroll
    for (int nf = 0; nf < 4; ++nf) {
      const int cl = wc * 64 + nf * 16 + fr;
#pragma unroll
      for (int rr = 0; rr < 4; ++rr) {
        const int ml = wr * 64 + mf * 16 + fq * 4 + rr;
        const int u = ml & 63, a = u >> 4;
        const int sperm = (ml & 64) | ((a >> 1) * 32 + ((u >> 2) & 3) * 8 +
                                       (a & 1) * 4 + (u & 3));
        smem[cl * 132 + sperm] = f2b(acc[mf][nf][rr]);
      }
    }
  __syncthreads();
  const int l5 = lane & 31;
  const size_t sbase = (size_t)((bm * 128) & 2047);
  const int bV = bm >> 4;
#pragma unroll
  for (int it = 0; it < 16; ++it) {
    const int rl = w * 32 + it * 2 + (lane >> 5);
    const int rowg = (bn - 16) * 128 + rl;
    const int h = rowg >> 6, d = rowg & 63;
    uint2 v = *(const uint2*)&smem[rl * 132 + l5 * 4];
    *(uint2*)&Vp[((size_t)(bV * 16 + h) * 64 + d) * 2048 + sbase + l5 * 4] = v;
  }
#undef GSTAGE
}

// ---------------------------------------------- attention variant A (LDS) ----
// Round-9 attn_q64, restricted to heads 0..15 (batch 0). grid 512.
__global__ __launch_bounds__(256) void attn_q64(
    const unsigned short* __restrict__ Qb, const unsigned short* __restrict__ Kb,
    const unsigned short* __restrict__ Vp, unsigned short* __restrict__ Ab) {
  __shared__ unsigned short smem[16384];

  const int tid = threadIdx.x, lane = tid & 63, w = tid >> 6;
  const int lo = lane & 15, hi = lane >> 4;

  const int id = blockIdx.x;
  const int qtr = id >> 7;      // 0..3
  const int g = (id >> 4) & 7;  // 0..7
  const int bh = id & 15;       // heads 0..15 (batch 0)
  const int bq = (qtr == 0)   ? 2 * g
                 : (qtr == 1) ? 2 * g + 1
                 : (qtr == 2) ? 31 - 2 * g
                              : 30 - 2 * g;
  const int qw = bq * 64 + w * 16;
  const size_t base = (size_t)bh * (2048 * 64);

  bf16x8 qf[2];
#pragma unroll
  for (int ks = 0; ks < 2; ++ks)
    qf[ks] =
        *(const bf16x8*)&Qb[base + (size_t)(qw + lo) * 64 + ks * 32 + hi * 8];

  f32x4 accO[4];
#pragma unroll
  for (int mf = 0; mf < 4; ++mf) accO[mf] = (f32x4)0.0f;
  float mrow = -1e30f, lpart = 0.0f;

  const int ntile = bq + 1;
  const unsigned short* kgb = Kb + base;
  const unsigned short* vgb = Vp + base;
  const int lseg = w * 512;

#define STAGE(BUF, KBASE)                                                    \
  {                                                                          \
    const int kb_ = (KBASE);                                                 \
    _Pragma("unroll") for (int qq = 0; qq < 2; ++qq) {                       \
      const int slot = qq * 256 + tid;                                       \
      const int row = slot >> 3, ch = (slot & 7) ^ (row & 7);                \
      gload16(kgb + (size_t)(kb_ + row) * 64 + ch * 8,                       \
              &smem[(BUF)*4096 + qq * 2048 + lseg]);                         \
      gload16(vgb + (size_t)row * 2048 + kb_ + ch * 8,                       \
              &smem[8192 + (BUF)*4096 + qq * 2048 + lseg]);                  \
    }                                                                        \
  }

  STAGE(0, 0)
  int cur = 0;

  for (int t = 0; t < ntile; ++t) {
    __syncthreads();
    if (t + 1 < ntile) STAGE(cur ^ 1, (t + 1) * 64)

    const int kb = t * 64;
    const int x7 = lo & 7;
    bf16x8 ka[2][4];
#pragma unroll
    for (int ks = 0; ks < 2; ++ks) {
      const int ch = (ks * 4 + hi) ^ x7;
#pragma unroll
      for (int kf = 0; kf < 4; ++kf)
        ka[ks][kf] =
            *(const bf16x8*)&smem[cur * 4096 + (kf * 16 + lo) * 64 + ch * 8];
    }
    f32x4 st[4];
#pragma unroll
    for (int kf = 0; kf < 4; ++kf) st[kf] = (f32x4)0.0f;
    __builtin_amdgcn_s_setprio(1);
#pragma unroll
    for (int ks = 0; ks < 2; ++ks)
#pragma unroll
      for (int kf = 0; kf < 4; ++kf)
        st[kf] = __builtin_amdgcn_mfma_f32_16x16x32_bf16(ka[ks][kf], qf[ks],
                                                         st[kf], 0, 0, 0);
    __builtin_amdgcn_s_setprio(0);

    bf16x8 va[2][4];
#pragma unroll
    for (int ks = 0; ks < 2; ++ks) {
      const int ch = (ks * 4 + hi) ^ x7;
#pragma unroll
      for (int mf = 0; mf < 4; ++mf)
        va[ks][mf] = *(const bf16x8*)&smem[8192 + cur * 4096 +
                                           (mf * 16 + lo) * 64 + ch * 8];
    }

    float v[16];
#pragma unroll
    for (int kf = 0; kf < 4; ++kf)
#pragma unroll
      for (int rr = 0; rr < 4; ++rr) v[kf * 4 + rr] = st[kf][rr];
    if (kb + 63 > qw) {
      const int qg = qw + lo;
#pragma unroll
      for (int kf = 0; kf < 4; ++kf)
#pragma unroll
        for (int rr = 0; rr < 4; ++rr)
          if (kb + kf * 16 + hi * 4 + rr > qg) v[kf * 4 + rr] = -1e30f;
    }
    float mx = fmaxf(fmaxf(fmaxf(v[0], v[1]), fmaxf(v[2], v[3])),
                     fmaxf(fmaxf(v[4], v[5]), fmaxf(v[6], v[7])));
    mx = fmaxf(mx, fmaxf(fmaxf(fmaxf(v[8], v[9]), fmaxf(v[10], v[11])),
                         fmaxf(fmaxf(v[12], v[13]), fmaxf(v[14], v[15]))));
    mx = fmaxf(mx, __shfl_xor(mx, 16));
    mx = fmaxf(mx, __shfl_xor(mx, 32));
    if (!__all(mx - mrow <= 64.0f)) {
      const float mnew = fmaxf(mrow, mx);
      const float al = fexp2((mrow - mnew) * EXPC2);
      mrow = mnew;
      lpart *= al;
#pragma unroll
      for (int mf = 0; mf < 4; ++mf)
#pragma unroll
        for (int rr = 0; rr < 4; ++rr) accO[mf][rr] *= al;
    }
    float p[16], rs = 0.0f;
#pragma unroll
    for (int i = 0; i < 16; ++i) {
      p[i] = fexp2((v[i] - mrow) * EXPC2);
      rs += p[i];
    }
    lpart += rs;

    bf16x8 pb[2];
#pragma unroll
    for (int ks = 0; ks < 2; ++ks) {
      uint4 u;
      u.x = cvtpk(p[ks * 8 + 0], p[ks * 8 + 1]);
      u.y = cvtpk(p[ks * 8 + 2], p[ks * 8 + 3]);
      u.z = cvtpk(p[ks * 8 + 4], p[ks * 8 + 5]);
      u.w = cvtpk(p[ks * 8 + 6], p[ks * 8 + 7]);
      pb[ks] = *(bf16x8*)&u;
    }

    __builtin_amdgcn_s_setprio(1);
#pragma unroll
    for (int ks = 0; ks < 2; ++ks)
#pragma unroll
      for (int mf = 0; mf < 4; ++mf)
        accO[mf] = __builtin_amdgcn_mfma_f32_16x16x32_bf16(va[ks][mf], pb[ks],
                                                           accO[mf], 0, 0, 0);
    __builtin_amdgcn_s_setprio(0);
    cur ^= 1;
  }

  __syncthreads();

  float l = lpart;
  l += __shfl_xor(l, 16);
  l += __shfl_xor(l, 32);
  const float linv = 1.0f / l;
  unsigned short* ot = &smem[w * 1152];
#pragma unroll
  for (int mf = 0; mf < 4; ++mf) {
    uint2 u;
    u.x = cvtpk(accO[mf][0] * linv, accO[mf][1] * linv);
    u.y = cvtpk(accO[mf][2] * linv, accO[mf][3] * linv);
    *(uint2*)&ot[lo * 72 + mf * 16 + hi * 4] = u;
  }
  const int b = bh >> 4, h = bh & 15;
  const int row = lane >> 2, cg = (lane & 3) * 16;
  uint4 o0 = *(const uint4*)&ot[row * 72 + cg];
  uint4 o1 = *(const uint4*)&ot[row * 72 + cg + 8];
  unsigned short* op = &Ab[(size_t)(b * 2048 + qw + row) * 1024 + h * 64 + cg];
  *(uint4*)op = o0;
  *(uint4*)(op + 8) = o1;
#undef STAGE
}

// --------------------------------------------- attention variant B (wave) ----
// 1-wave 64-thread blocks, zero LDS/barriers. Heads 16..31 (batch 1).
// grid 1024: bh = 16 + (id&15) (2 heads per XCD), t32 = 63 - (id>>4) (LPT).
// Wave math identical to round-10 attn_nolds (correctness-verified).
__global__ __launch_bounds__(64) void attn_wave(
    const unsigned short* __restrict__ Qb, const unsigned short* __restrict__ Kb,
    const unsigned short* __restrict__ Vp, unsigned short* __restrict__ Ab) {
  const int lane = threadIdx.x & 63;
  const int lo = lane & 15, hi = lane >> 4;

  const int id = blockIdx.x;
  const int bh = 16 + (id & 15);     // batch 1; head h on XCD (h&7): 2 heads/XCD
  const int t32 = 63 - (id >> 4);    // LPT: longest kv-prefix first
  const int qw = t32 * 32;
  const int ntile = (t32 >> 1) + 1;
  const size_t base = (size_t)bh * (2048 * 64);
  const unsigned short* kg = Kb + base;
  const unsigned short* vg = Vp + base;

  bf16x8 qf[2][2];
#pragma unroll
  for (int qn = 0; qn < 2; ++qn)
#pragma unroll
    for (int ks = 0; ks < 2; ++ks)
      qf[qn][ks] = *(const bf16x8*)&Qb[base +
                                       (size_t)(qw + qn * 16 + lo) * 64 +
                                       ks * 32 + hi * 8];

  f32x4 accO[4][2];
#pragma unroll
  for (int mf = 0; mf < 4; ++mf)
#pragma unroll
    for (int qn = 0; qn < 2; ++qn) accO[mf][qn] = (f32x4)0.0f;
  float mrow[2] = {-1e30f, -1e30f}, lpart[2] = {0.0f, 0.0f};

  bf16x8 kaA[2][4], kaB[2][4];
#define LOADK(DST, KB_)                                                      \
  _Pragma("unroll") for (int ks = 0; ks < 2; ++ks)                           \
      _Pragma("unroll") for (int kf = 0; kf < 4; ++kf) DST[ks][kf] =         \
          *(const bf16x8*)&kg[(size_t)((KB_) + kf * 16 + lo) * 64 +          \
                              ks * 32 + hi * 8];

#define ATILE(T, KA, KN)                                                     \
  {                                                                          \
    const int kb = (T) * 64;                                                 \
    f32x4 st[4][2];                                                          \
    _Pragma("unroll") for (int kf = 0; kf < 4; ++kf)                         \
        _Pragma("unroll") for (int qn = 0; qn < 2; ++qn) st[kf][qn] =        \
            (f32x4)0.0f;                                                     \
    __builtin_amdgcn_s_setprio(1);                                           \
    _Pragma("unroll") for (int ks = 0; ks < 2; ++ks)                         \
        _Pragma("unroll") for (int kf = 0; kf < 4; ++kf)                     \
            _Pragma("unroll") for (int qn = 0; qn < 2; ++qn) st[kf][qn] =    \
                __builtin_amdgcn_mfma_f32_16x16x32_bf16(                     \
                    KA[ks][kf], qf[qn][ks], st[kf][qn], 0, 0, 0);            \
    __builtin_amdgcn_s_setprio(0);                                           \
    if ((T) + 1 < ntile) LOADK(KN, ((T) + 1) * 64)                           \
    bf16x8 va[2][4];                                                         \
    _Pragma("unroll") for (int ks = 0; ks < 2; ++ks)                         \
        _Pragma("unroll") for (int mf = 0; mf < 4; ++mf) va[ks][mf] =        \
            *(const bf16x8*)&vg[(size_t)(mf * 16 + lo) * 2048 + kb +         \
                                ks * 32 + hi * 8];                           \
    bf16x8 pb[2][2];                                                         \
    _Pragma("unroll") for (int qn = 0; qn < 2; ++qn) {                       \
      float v[16];                                                           \
      _Pragma("unroll") for (int kf = 0; kf < 4; ++kf)                       \
          _Pragma("unroll") for (int rr = 0; rr < 4; ++rr) v[kf * 4 + rr] =  \
              st[kf][qn][rr];                                                \
      if (kb + 63 > qw) {                                                    \
        const int qg = qw + qn * 16 + lo;                                    \
        _Pragma("unroll") for (int kf = 0; kf < 4; ++kf)                     \
            _Pragma("unroll") for (int rr = 0; rr < 4; ++rr) if (kb +        \
                kf * 16 + hi * 4 + rr > qg) v[kf * 4 + rr] = -1e30f;         \
      }                                                                      \
      float mx = fmaxf(fmaxf(fmaxf(v[0], v[1]), fmaxf(v[2], v[3])),          \
                       fmaxf(fmaxf(v[4], v[5]), fmaxf(v[6], v[7])));         \
      mx = fmaxf(mx, fmaxf(fmaxf(fmaxf(v[8], v[9]), fmaxf(v[10], v[11])),    \
                           fmaxf(fmaxf(v[12], v[13]), fmaxf(v[14], v[15]))));\
      mx = fmaxf(mx, __shfl_xor(mx, 16));                                    \
      mx = fmaxf(mx, __shfl_xor(mx, 32));                                    \
      if (!__all(mx - mrow[qn] <= 64.0f)) {                                  \
        const float mnew = fmaxf(mrow[qn], mx);                              \
        const float al = fexp2((mrow[qn] - mnew) * EXPC2);                   \
        mrow[qn] = mnew;                                                     \
        lpart[qn] *= al;                                                     \
        _Pragma("unroll") for (int mf = 0; mf < 4; ++mf)                     \
            _Pragma("unroll") for (int rr = 0; rr < 4; ++rr)                 \
                accO[mf][qn][rr] *= al;                                      \
      }                                                                      \
      float p[16], rs = 0.0f;                                                \
      _Pragma("unroll") for (int i = 0; i < 16; ++i) {                       \
        p[i] = fexp2((v[i] - mrow[qn]) * EXPC2);                             \
        rs += p[i];                                                          \
      }                                                                      \
      lpart[qn] += rs;                                                       \
      _Pragma("unroll") for (int ks = 0; ks < 2; ++ks) {                     \
        uint4 u;                                                             \
        u.x = cvtpk(p[ks * 8 + 0], p[ks * 8 + 1]);                           \
        u.y = cvtpk(p[ks * 8 + 2], p[ks * 8 + 3]);                           \
        u.z = cvtpk(p[ks * 8 + 4], p[ks * 8 + 5]);                           \
        u.w = cvtpk(p[ks * 8 + 6], p[ks * 8 + 7]);                           \
        pb[qn][ks] = *(bf16x8*)&u;                                           \
      }                                                                      \
    }                                                                        \
    __builtin_amdgcn_s_setprio(1);                                           \
    _Pragma("unroll") for (int ks = 0; ks < 2; ++ks)                         \
        _Pragma("unroll") for (int mf = 0; mf < 4; ++mf)                     \
            _Pragma("unroll") for (int qn = 0; qn < 2; ++qn) accO[mf][qn] =  \
                __builtin_amdgcn_mfma_f32_16x16x32_bf16(                     \
                    va[ks][mf], pb[qn][ks], accO[mf][qn], 0, 0, 0);          \
    __builtin_amdgcn_s_setprio(0);                                           \
  }

  LOADK(kaA, 0)
  int t = 0;
  while (true) {
    ATILE(t, kaA, kaB)
    if (++t >= ntile) break;
    ATILE(t, kaB, kaA)
    if (++t >= ntile) break;
  }

  const int b = bh >> 4, h = bh & 15;
#pragma unroll
  for (int qn = 0; qn < 2; ++qn) {
    float l = lpart[qn];
    l += __shfl_xor(l, 16);
    l += __shfl_xor(l, 32);
    const float linv = 1.0f / l;
#pragma unroll
    for (int mf = 0; mf < 4; ++mf) {
      uint2 u;
      u.x = cvtpk(accO[mf][qn][0] * linv, accO[mf][qn][1] * linv);
      u.y = cvtpk(accO[mf][qn][2] * linv, accO[mf][qn][3] * linv);
      *(uint2*)&Ab[(size_t)(b * 2048 + qw + qn * 16 + lo) * 1024 + h * 64 +
                   mf * 16 + hi * 4] = u;
    }
  }
#undef ATILE
#undef LOADK
}

// -------------------------------------------------------------- launch ----
extern "C" void kernel_launch(void* const* d_in, const int* in_sizes, int n_in,
                              void* d_out, int out_size, void* d_ws,
                              size_t ws_size, hipStream_t stream) {
  (void)in_sizes; (void)n_in; (void)out_size; (void)ws_size;
  const float* x = (const float*)d_in[0];
  const float* Wq = (const float*)d_in[1];
  const float* Wk = (const float*)d_in[2];
  const float* Wv = (const float*)d_in[3];
  const float* Wo = (const float*)d_in[4];
  float* out = (float*)d_out;

  char* ws = (char*)d_ws;
  unsigned short* xb = (unsigned short*)(ws);                // 8MB
  unsigned short* Wt = (unsigned short*)(ws + (8u << 20));   // 4x2MB (q,k,v,o)
  unsigned short* Qb = (unsigned short*)(ws + (16u << 20));  // 8MB
  unsigned short* Kb = (unsigned short*)(ws + (24u << 20));  // 8MB
  unsigned short* Vp = (unsigned short*)(ws + (32u << 20));  // 8MB
  unsigned short* Ab = (unsigned short*)(ws + (40u << 20));  // 8MB
  unsigned short* Wto = Wt + (size_t)3 * 1024 * 1024;        // ELEMENT offset

  prep<<<dim3(5120), 256, 0, stream>>>(x, Wq, Wk, Wv, Wo, xb, Wt);
  gemm2ph<0><<<dim3(768), 256, 0, stream>>>(xb, Wt, Qb, Kb, Vp, nullptr);
  attn_q64<<<dim3(512), 256, 0, stream>>>(Qb, Kb, Vp, Ab);    // heads 0..15
  attn_wave<<<dim3(1024), 64, 0, stream>>>(Qb, Kb, Vp, Ab);   // heads 16..31
  gemm2ph<1><<<dim3(256), 256, 0, stream>>>(Ab, Wto, nullptr, nullptr, nullptr,
                                            out);
}

// Round 12
// 108.088 us; speedup vs baseline: 1.6589x; 1.3595x over previous
//
#include <hip/hip_runtime.h>

// MHA forward, round 12.
//  - attention: round-9 attn_q64 for ALL heads (A/B winner; wave variant 2.2x worse/work)
//  - QKV GEMM: NEW 256x256-tile, 8-wave, wave-tile 64x128 (LDS bytes/FLOP x0.75,
//    half the iterations; grid 192). Same verified swizzle formulas.
//  - out GEMM: round-9 128^2 2-phase (unchanged).
// B=2, S=2048, D=1024, H=16, DH=64, scale=1/32 folded into exp2 constant.
//
// ws: xb 8@0 | Wt 8@8 | Qb 8@16 | Kb 8@24 | Vp 8@32 | Ab 8@40  (48MB)

#define AS1 __attribute__((address_space(1)))
#define AS3 __attribute__((address_space(3)))
#define EXPC2 0.04508422f  // (1/32) * log2(e)

typedef __attribute__((ext_vector_type(4))) float f32x4;
typedef __attribute__((ext_vector_type(8))) short bf16x8;

__device__ __forceinline__ void gload16(const void* g, void* l) {
  __builtin_amdgcn_global_load_lds((const AS1 unsigned int*)g,
                                   (AS3 unsigned int*)l, 16, 0, 0);
}
__device__ __forceinline__ unsigned short f2b(float f) {  // RNE fp32->bf16
  unsigned u = __float_as_uint(f);
  return (unsigned short)((u + 0x7FFFu + ((u >> 16) & 1u)) >> 16);
}
__device__ __forceinline__ float fexp2(float x) {
  float r;
  asm("v_exp_f32 %0, %1" : "=v"(r) : "v"(x));
  return r;
}
__device__ __forceinline__ unsigned cvtpk(float a, float b) {  // [a|b] bf16x2
  unsigned r;
  asm("v_cvt_pk_bf16_f32 %0, %1, %2" : "=v"(r) : "v"(a), "v"(b));
  return r;
}

// ---------------------------------------------------------------- prep ----
__global__ __launch_bounds__(256) void prep(
    const float* __restrict__ x, const float* __restrict__ W0,
    const float* __restrict__ W1, const float* __restrict__ W2,
    const float* __restrict__ W3, unsigned short* __restrict__ xb,
    unsigned short* __restrict__ Wt) {
  __shared__ float T[64][65];
  const int tid = threadIdx.x;
  const int bid = blockIdx.x;
  if (bid < 4096) {
    const size_t i = (size_t)(bid * 256 + tid) * 4;
    float4 v = *(const float4*)&x[i];
    uint2 o;
    o.x = f2b(v.x) | ((unsigned)f2b(v.y) << 16);
    o.y = f2b(v.z) | ((unsigned)f2b(v.w) << 16);
    *(uint2*)&xb[i] = o;
    return;
  }
  const int idx = bid - 4096;
  const int kb = (idx & 15) * 64, nb = ((idx >> 4) & 15) * 64, z = idx >> 8;
  const float* W = (z == 0) ? W0 : (z == 1) ? W1 : (z == 2) ? W2 : W3;
  unsigned short* D = Wt + (size_t)z * 1024 * 1024;
#pragma unroll
  for (int p = 0; p < 4; ++p) {
    const int s = p * 256 + tid;
    const int r = s >> 4, c4 = s & 15;
    float4 v = *(const float4*)&W[(size_t)(kb + r) * 1024 + nb + c4 * 4];
    T[r][c4 * 4 + 0] = v.x;
    T[r][c4 * 4 + 1] = v.y;
    T[r][c4 * 4 + 2] = v.z;
    T[r][c4 * 4 + 3] = v.w;
  }
  __syncthreads();
#pragma unroll
  for (int p = 0; p < 4; ++p) {
    const int s = p * 256 + tid;
    const int n = s >> 4, k4 = s & 15;
    uint2 o;
    o.x = f2b(T[k4 * 4 + 0][n]) | ((unsigned)f2b(T[k4 * 4 + 1][n]) << 16);
    o.y = f2b(T[k4 * 4 + 2][n]) | ((unsigned)f2b(T[k4 * 4 + 3][n]) << 16);
    *(uint2*)&D[(size_t)(nb + n) * 1024 + kb + k4 * 4] = o;
  }
}

// ------------------------------------------------------------ gemm_qkv ----
// C[4096 x 3072] = xb @ Wt^T. 256x256 tile, BK=32, 8 waves (4m x 2n),
// wave-tile 64x128 (acc[4][8]). dbuf LDS, row-pair-packed XOR swizzle
// (round-9 verified involution). Grid 192: bm = id/12, bn = id%12.
// bn 0-3 -> Q scatter, 4-7 -> K scatter, 8-11 -> Vp sigma-permuted via
// 4 sequential 128x128 LDS-transpose quadrants.
__global__ __launch_bounds__(512, 2) void gemm_qkv(
    const unsigned short* __restrict__ xb, const unsigned short* __restrict__ Wt,
    unsigned short* __restrict__ Qb, unsigned short* __restrict__ Kb,
    unsigned short* __restrict__ Vp) {
  // ushort idx: A0@0, B0@8192, A1@16384, B1@24576 (each 256x32 = 8192).
  // V slab [128][132] (16896) aliases @0 after the loop.
  __shared__ unsigned short smem[32768];

  const int tid = threadIdx.x, lane = tid & 63, w = tid >> 6;  // w 0..7
  const int bm = blockIdx.x / 12, bn = blockIdx.x % 12;
  const int wr = w >> 1, wc = w & 1;

  f32x4 acc[4][8];
#pragma unroll
  for (int m = 0; m < 4; ++m)
#pragma unroll
    for (int n = 0; n < 8; ++n) acc[m][n] = (f32x4)0.0f;

  // staging source swizzle (write side): call c covers phys rows c*8..c*8+7
  const int lu = (lane & 7) ^ (lane >> 3);
  const int srow2 = 2 * (lane >> 3) + (lu >> 2);
  const int scol2 = (lu & 3) * 8;
  const int c0 = w * 2, c1 = w * 2 + 1;
  const size_t arow0 = (size_t)(bm * 256 + c0 * 16 + srow2) * 1024 + scol2;
  const size_t arow1 = (size_t)(bm * 256 + c1 * 16 + srow2) * 1024 + scol2;
  const size_t brow0 = (size_t)(bn * 256 + c0 * 16 + srow2) * 1024 + scol2;
  const size_t brow1 = (size_t)(bn * 256 + c1 * 16 + srow2) * 1024 + scol2;

  // fragment read swizzle (read side)
  const int fr = lane & 15, g = lane >> 4;
  const int fh = fr >> 1;
  const int pcx = ((((fr & 1) << 2) | g) ^ fh) * 8;

#define QSTAGE(BUF, KC)                                                      \
  {                                                                          \
    gload16(&xb[arow0 + (KC)], &smem[(BUF)*16384 + c0 * 512]);               \
    gload16(&xb[arow1 + (KC)], &smem[(BUF)*16384 + c1 * 512]);               \
    gload16(&Wt[brow0 + (KC)], &smem[8192 + (BUF)*16384 + c0 * 512]);        \
    gload16(&Wt[brow1 + (KC)], &smem[8192 + (BUF)*16384 + c1 * 512]);        \
  }

  QSTAGE(0, 0)
  int cur = 0;

  for (int t = 0; t < 32; ++t) {
    __syncthreads();  // drains vmcnt -> buf[cur] resident
    if (t + 1 < 32) QSTAGE(cur ^ 1, (t + 1) * 32)

    bf16x8 af[4], bf[8];
#pragma unroll
    for (int m = 0; m < 4; ++m)
      af[m] = *(const bf16x8*)&smem[cur * 16384 + (wr * 32 + m * 8 + fh) * 64 +
                                    pcx];
#pragma unroll
    for (int n = 0; n < 8; ++n)
      bf[n] = *(const bf16x8*)&smem[8192 + cur * 16384 +
                                    (wc * 64 + n * 8 + fh) * 64 + pcx];
#pragma unroll
    for (int m = 0; m < 4; ++m)
#pragma unroll
      for (int n = 0; n < 8; ++n)
        acc[m][n] = __builtin_amdgcn_mfma_f32_16x16x32_bf16(af[m], bf[n],
                                                            acc[m][n], 0, 0, 0);
    cur ^= 1;
  }

  const int fq = lane >> 4;
  if (bn < 8) {
    // ---- Q / K scatter epilogue ----
    unsigned short* Ob = (bn < 4) ? Qb : Kb;
    const int cbase = (bn & 3) * 256;
#pragma unroll
    for (int mf = 0; mf < 4; ++mf)
#pragma unroll
      for (int nf = 0; nf < 8; ++nf) {
        const int col = cbase + wc * 128 + nf * 16 + fr;  // 0..1023
        const int h = col >> 6, d = col & 63;
#pragma unroll
        for (int rr = 0; rr < 4; ++rr) {
          const int m = bm * 256 + wr * 64 + mf * 16 + fq * 4 + rr;
          const int b = m >> 11, s = m & 2047;
          Ob[((size_t)(b * 16 + h) * 2048 + s) * 64 + d] = f2b(acc[mf][nf][rr]);
        }
      }
    return;
  }

  // ---- V epilogue: 4 sequential 128x128 quadrants via slab [128][132] ----
  const int chb = (bn - 8) * 256;
  const int s0all = bm * 256;
  const int b = s0all >> 11;
#pragma unroll
  for (int qq = 0; qq < 4; ++qq) {
    const int qm = qq >> 1, qn = qq & 1;
    __syncthreads();  // prev quadrant's stores done / staging LDS dead
    if (wc == qn && (wr >> 1) == qm) {
#pragma unroll
      for (int mf = 0; mf < 4; ++mf)
#pragma unroll
        for (int nf = 0; nf < 8; ++nf) {
          const int cl = nf * 16 + fr;  // local channel col 0..127
#pragma unroll
          for (int rr = 0; rr < 4; ++rr) {
            const int ml = (wr & 1) * 64 + mf * 16 + fq * 4 + rr;  // local s
            const int u = ml & 63, a = u >> 4;
            const int sperm = (ml & 64) | ((a >> 1) * 32 + ((u >> 2) & 3) * 8 +
                                           (a & 1) * 4 + (u & 3));
            smem[cl * 132 + sperm] = f2b(acc[mf][nf][rr]);
          }
        }
    }
    __syncthreads();
    // cooperative coalesced store: 512 threads, 64B runs along s
    const int row = tid >> 2, cg = (tid & 3) * 32;
    const int ch = chb + qn * 128 + row;
    const int h = ch >> 6, d = ch & 63;
    const int sb = (s0all + qm * 128) & 2047;
    unsigned short* dst = &Vp[((size_t)(b * 16 + h) * 64 + d) * 2048 + sb + cg];
    *(uint4*)(dst + 0) = *(const uint4*)&smem[row * 132 + cg];
    *(uint4*)(dst + 8) = *(const uint4*)&smem[row * 132 + cg + 8];
    *(uint4*)(dst + 16) = *(const uint4*)&smem[row * 132 + cg + 16];
    *(uint4*)(dst + 24) = *(const uint4*)&smem[row * 132 + cg + 24];
  }
#undef QSTAGE
}

// ------------------------------------------------------------ gemm_out ----
// Round-9 exact 128^2 2-phase dbuf, swizzled LDS. grid 256 linear.
__global__ __launch_bounds__(256) void gemm_out(
    const unsigned short* __restrict__ A, const unsigned short* __restrict__ B,
    float* __restrict__ Of) {
  __shared__ unsigned short smem[16384];

  const int tid = threadIdx.x, lane = tid & 63, w = tid >> 6;
  const int bm = blockIdx.x >> 3, bn = blockIdx.x & 7;
  const int wr = w >> 1, wc = w & 1;

  f32x4 acc[4][4];
#pragma unroll
  for (int m = 0; m < 4; ++m)
#pragma unroll
    for (int n = 0; n < 4; ++n) acc[m][n] = (f32x4)0.0f;

  const int lu = (lane & 7) ^ (lane >> 3);
  const int srow2 = 2 * (lane >> 3) + (lu >> 2);
  const int scol2 = (lu & 3) * 8;
  const size_t arow = (size_t)(bm * 128 + srow2) * 1024 + scol2;
  const size_t brow = (size_t)(bn * 128 + srow2) * 1024 + scol2;

  const int fr = lane & 15, g = lane >> 4;
  const int fh = fr >> 1;
  const int pcx = ((((fr & 1) << 2) | g) ^ fh) * 8;

#define OSTAGE(BUF, KC)                                                      \
  {                                                                          \
    _Pragma("unroll") for (int q = 0; q < 2; ++q) {                          \
      const int r = w * 32 + q * 16;                                         \
      gload16(&A[arow + (size_t)r * 1024 + (KC)],                            \
              &smem[(BUF) * 8192 + r * 32]);                                 \
      gload16(&B[brow + (size_t)r * 1024 + (KC)],                            \
              &smem[(BUF) * 8192 + 4096 + r * 32]);                          \
    }                                                                        \
  }

  OSTAGE(0, 0)
  int cur = 0;

  for (int t = 0; t < 32; ++t) {
    __syncthreads();
    if (t + 1 < 32) OSTAGE(cur ^ 1, (t + 1) * 32)

    bf16x8 af[4], bf[4];
#pragma unroll
    for (int m = 0; m < 4; ++m)
      af[m] = *(const bf16x8*)&smem[cur * 8192 + (wr * 32 + m * 8 + fh) * 64 +
                                    pcx];
#pragma unroll
    for (int n = 0; n < 4; ++n)
      bf[n] = *(const bf16x8*)&smem[cur * 8192 + 4096 +
                                    (wc * 32 + n * 8 + fh) * 64 + pcx];
#pragma unroll
    for (int m = 0; m < 4; ++m)
#pragma unroll
      for (int n = 0; n < 4; ++n)
        acc[m][n] = __builtin_amdgcn_mfma_f32_16x16x32_bf16(af[m], bf[n],
                                                            acc[m][n], 0, 0, 0);
    cur ^= 1;
  }

  const int fq = lane >> 4;
#pragma unroll
  for (int mf = 0; mf < 4; ++mf)
#pragma unroll
    for (int nf = 0; nf < 4; ++nf) {
      const int col = bn * 128 + wc * 64 + nf * 16 + fr;
#pragma unroll
      for (int rr = 0; rr < 4; ++rr) {
        const int m = bm * 128 + wr * 64 + mf * 16 + fq * 4 + rr;
        Of[(size_t)m * 1024 + col] = acc[mf][nf][rr];
      }
    }
#undef OSTAGE
}

// ----------------------------------------------------------- attention ----
// Round-9 attn_q64 (A/B winner), all 32 heads. grid 1024, balanced bq map.
__global__ __launch_bounds__(256) void attn_q64(
    const unsigned short* __restrict__ Qb, const unsigned short* __restrict__ Kb,
    const unsigned short* __restrict__ Vp, unsigned short* __restrict__ Ab) {
  __shared__ unsigned short smem[16384];

  const int tid = threadIdx.x, lane = tid & 63, w = tid >> 6;
  const int lo = lane & 15, hi = lane >> 4;

  const int id = blockIdx.x;
  const int qtr = id >> 8;      // 0..3
  const int g = (id >> 5) & 7;  // 0..7
  const int bh = id & 31;
  const int bq = (qtr == 0)   ? 2 * g
                 : (qtr == 1) ? 2 * g + 1
                 : (qtr == 2) ? 31 - 2 * g
                              : 30 - 2 * g;
  const int qw = bq * 64 + w * 16;
  const size_t base = (size_t)bh * (2048 * 64);

  bf16x8 qf[2];
#pragma unroll
  for (int ks = 0; ks < 2; ++ks)
    qf[ks] =
        *(const bf16x8*)&Qb[base + (size_t)(qw + lo) * 64 + ks * 32 + hi * 8];

  f32x4 accO[4];
#pragma unroll
  for (int mf = 0; mf < 4; ++mf) accO[mf] = (f32x4)0.0f;
  float mrow = -1e30f, lpart = 0.0f;

  const int ntile = bq + 1;
  const unsigned short* kgb = Kb + base;
  const unsigned short* vgb = Vp + base;
  const int lseg = w * 512;

#define STAGE(BUF, KBASE)                                                    \
  {                                                                          \
    const int kb_ = (KBASE);                                                 \
    _Pragma("unroll") for (int qq = 0; qq < 2; ++qq) {                       \
      const int slot = qq * 256 + tid;                                       \
      const int row = slot >> 3, ch = (slot & 7) ^ (row & 7);                \
      gload16(kgb + (size_t)(kb_ + row) * 64 + ch * 8,                       \
              &smem[(BUF)*4096 + qq * 2048 + lseg]);                         \
      gload16(vgb + (size_t)row * 2048 + kb_ + ch * 8,                       \
              &smem[8192 + (BUF)*4096 + qq * 2048 + lseg]);                  \
    }                                                                        \
  }

  STAGE(0, 0)
  int cur = 0;

  for (int t = 0; t < ntile; ++t) {
    __syncthreads();
    if (t + 1 < ntile) STAGE(cur ^ 1, (t + 1) * 64)

    const int kb = t * 64;
    const int x7 = lo & 7;
    bf16x8 ka[2][4];
#pragma unroll
    for (int ks = 0; ks < 2; ++ks) {
      const int ch = (ks * 4 + hi) ^ x7;
#pragma unroll
      for (int kf = 0; kf < 4; ++kf)
        ka[ks][kf] =
            *(const bf16x8*)&smem[cur * 4096 + (kf * 16 + lo) * 64 + ch * 8];
    }
    f32x4 st[4];
#pragma unroll
    for (int kf = 0; kf < 4; ++kf) st[kf] = (f32x4)0.0f;
    __builtin_amdgcn_s_setprio(1);
#pragma unroll
    for (int ks = 0; ks < 2; ++ks)
#pragma unroll
      for (int kf = 0; kf < 4; ++kf)
        st[kf] = __builtin_amdgcn_mfma_f32_16x16x32_bf16(ka[ks][kf], qf[ks],
                                                         st[kf], 0, 0, 0);
    __builtin_amdgcn_s_setprio(0);

    bf16x8 va[2][4];
#pragma unroll
    for (int ks = 0; ks < 2; ++ks) {
      const int ch = (ks * 4 + hi) ^ x7;
#pragma unroll
      for (int mf = 0; mf < 4; ++mf)
        va[ks][mf] = *(const bf16x8*)&smem[8192 + cur * 4096 +
                                           (mf * 16 + lo) * 64 + ch * 8];
    }

    float v[16];
#pragma unroll
    for (int kf = 0; kf < 4; ++kf)
#pragma unroll
      for (int rr = 0; rr < 4; ++rr) v[kf * 4 + rr] = st[kf][rr];
    if (kb + 63 > qw) {
      const int qg = qw + lo;
#pragma unroll
      for (int kf = 0; kf < 4; ++kf)
#pragma unroll
        for (int rr = 0; rr < 4; ++rr)
          if (kb + kf * 16 + hi * 4 + rr > qg) v[kf * 4 + rr] = -1e30f;
    }
    float mx = fmaxf(fmaxf(fmaxf(v[0], v[1]), fmaxf(v[2], v[3])),
                     fmaxf(fmaxf(v[4], v[5]), fmaxf(v[6], v[7])));
    mx = fmaxf(mx, fmaxf(fmaxf(fmaxf(v[8], v[9]), fmaxf(v[10], v[11])),
                         fmaxf(fmaxf(v[12], v[13]), fmaxf(v[14], v[15]))));
    mx = fmaxf(mx, __shfl_xor(mx, 16));
    mx = fmaxf(mx, __shfl_xor(mx, 32));
    if (!__all(mx - mrow <= 64.0f)) {
      const float mnew = fmaxf(mrow, mx);
      const float al = fexp2((mrow - mnew) * EXPC2);
      mrow = mnew;
      lpart *= al;
#pragma unroll
      for (int mf = 0; mf < 4; ++mf)
#pragma unroll
        for (int rr = 0; rr < 4; ++rr) accO[mf][rr] *= al;
    }
    float p[16], rs = 0.0f;
#pragma unroll
    for (int i = 0; i < 16; ++i) {
      p[i] = fexp2((v[i] - mrow) * EXPC2);
      rs += p[i];
    }
    lpart += rs;

    bf16x8 pb[2];
#pragma unroll
    for (int ks = 0; ks < 2; ++ks) {
      uint4 u;
      u.x = cvtpk(p[ks * 8 + 0], p[ks * 8 + 1]);
      u.y = cvtpk(p[ks * 8 + 2], p[ks * 8 + 3]);
      u.z = cvtpk(p[ks * 8 + 4], p[ks * 8 + 5]);
      u.w = cvtpk(p[ks * 8 + 6], p[ks * 8 + 7]);
      pb[ks] = *(bf16x8*)&u;
    }

    __builtin_amdgcn_s_setprio(1);
#pragma unroll
    for (int ks = 0; ks < 2; ++ks)
#pragma unroll
      for (int mf = 0; mf < 4; ++mf)
        accO[mf] = __builtin_amdgcn_mfma_f32_16x16x32_bf16(va[ks][mf], pb[ks],
                                                           accO[mf], 0, 0, 0);
    __builtin_amdgcn_s_setprio(0);
    cur ^= 1;
  }

  __syncthreads();

  float l = lpart;
  l += __shfl_xor(l, 16);
  l += __shfl_xor(l, 32);
  const float linv = 1.0f / l;
  unsigned short* ot = &smem[w * 1152];
#pragma unroll
  for (int mf = 0; mf < 4; ++mf) {
    uint2 u;
    u.x = cvtpk(accO[mf][0] * linv, accO[mf][1] * linv);
    u.y = cvtpk(accO[mf][2] * linv, accO[mf][3] * linv);
    *(uint2*)&ot[lo * 72 + mf * 16 + hi * 4] = u;
  }
  const int b = bh >> 4, h = bh & 15;
  const int row = lane >> 2, cg = (lane & 3) * 16;
  uint4 o0 = *(const uint4*)&ot[row * 72 + cg];
  uint4 o1 = *(const uint4*)&ot[row * 72 + cg + 8];
  unsigned short* op = &Ab[(size_t)(b * 2048 + qw + row) * 1024 + h * 64 + cg];
  *(uint4*)op = o0;
  *(uint4*)(op + 8) = o1;
#undef STAGE
}

// -------------------------------------------------------------- launch ----
extern "C" void kernel_launch(void* const* d_in, const int* in_sizes, int n_in,
                              void* d_out, int out_size, void* d_ws,
                              size_t ws_size, hipStream_t stream) {
  (void)in_sizes; (void)n_in; (void)out_size; (void)ws_size;
  const float* x = (const float*)d_in[0];
  const float* Wq = (const float*)d_in[1];
  const float* Wk = (const float*)d_in[2];
  const float* Wv = (const float*)d_in[3];
  const float* Wo = (const float*)d_in[4];
  float* out = (float*)d_out;

  char* ws = (char*)d_ws;
  unsigned short* xb = (unsigned short*)(ws);                // 8MB
  unsigned short* Wt = (unsigned short*)(ws + (8u << 20));   // 4x2MB (q,k,v,o)
  unsigned short* Qb = (unsigned short*)(ws + (16u << 20));  // 8MB
  unsigned short* Kb = (unsigned short*)(ws + (24u << 20));  // 8MB
  unsigned short* Vp = (unsigned short*)(ws + (32u << 20));  // 8MB
  unsigned short* Ab = (unsigned short*)(ws + (40u << 20));  // 8MB
  unsigned short* Wto = Wt + (size_t)3 * 1024 * 1024;        // ELEMENT offset

  prep<<<dim3(5120), 256, 0, stream>>>(x, Wq, Wk, Wv, Wo, xb, Wt);
  gemm_qkv<<<dim3(192), 512, 0, stream>>>(xb, Wt, Qb, Kb, Vp);
  attn_q64<<<dim3(1024), 256, 0, stream>>>(Qb, Kb, Vp, Ab);
  gemm_out<<<dim3(256), 256, 0, stream>>>(Ab, Wto, out);
}